// Round 7
// baseline (76.553 us; speedup 1.0000x reference)
//
#include <hip/hip_runtime.h>

#define IMG_H 256
#define IMG_W 256
#define ROWS 8
#define STRIPS (IMG_H / ROWS)      // 32 strips per image
#define NIMG 128
#define NWAVES (NIMG * STRIPS)     // 4096 waves, one per 8-row strip

// Schedule fence: nothing moves across. Used to stop cross-STEP software
// pipelining that inflated VGPR to 248 (R6) -> occupancy collapse.
#define SB() __builtin_amdgcn_sched_barrier(0)

__device__ __forceinline__ float pullf(int addr, float v) {
    return __int_as_float(__builtin_amdgcn_ds_bpermute(addr, __float_as_int(v)));
}

__device__ __forceinline__ float4 f4fma(float w, float4 a, float4 b) {
    return make_float4(fmaf(w, a.x, b.x), fmaf(w, a.y, b.y),
                       fmaf(w, a.z, b.z), fmaf(w, a.w, b.w));
}

__device__ __forceinline__ float4 f4mul(float4 a, float4 b) {
    return make_float4(a.x * b.x, a.y * b.y, a.z * b.z, a.w * b.w);
}

__device__ __forceinline__ float4 f4scale(float w, float4 a) {
    return make_float4(w * a.x, w * a.y, w * a.z, w * a.w);
}

__device__ __forceinline__ float ssim1(float mu1, float mu2, float spp, float stt, float spt) {
    const float C1 = 1e-4f, C2 = 9e-4f;
    float mu1s = mu1 * mu1, mu2s = mu2 * mu2, mu12 = mu1 * mu2;
    float s1 = spp - mu1s, s2 = stt - mu2s, s12 = spt - mu12;
    float num = (2.f * mu12 + C1) * (2.f * s12 + C2);
    float den = (mu1s + mu2s + C1) * (s1 + s2 + C2);
    return num * __builtin_amdgcn_rcpf(den);   // rel err ~1e-6; output is a mean
}

// V-first separable SSIM. One wave = one 8-row strip, float4/lane = 256 cols.
// Window: RAW rows only (2 x 8 x float4 = 64 VGPR), mod-8 static slots.
// Quantities sequential; sched_barrier(0) fences pin the live-set (~115) so
// the allocator can't pipeline across quantities/steps. No launch-bound min
// (R4/R5: min-waves attr => 64-reg forced alloc + 427MB scratch spill).
template<int ATOMIC>
__global__ __launch_bounds__(256) void ssim_main(
    const float* __restrict__ pred,
    const float* __restrict__ targ,
    const float* __restrict__ window,
    float* __restrict__ wsum)
{
    const int lane = threadIdx.x & 63;
    const int wid  = threadIdx.x >> 6;
    const int gw   = blockIdx.x * 4 + wid;   // 0..4095
    const int n    = gw >> 5;                // image
    const int s    = gw & 31;                // strip
    const int r0   = s * ROWS;
    const int c    = lane << 2;

    // exact 1D gaussian: g[j] = w2d[3][j] / sum_j w2d[3][j]
    float g[7];
    {
        float sum = 0.f;
#pragma unroll
        for (int j = 0; j < 7; ++j) { g[j] = window[21 + j]; sum += g[j]; }
        float inv = 1.f / sum;
#pragma unroll
        for (int j = 0; j < 7; ++j) g[j] *= inv;
    }

    const float* pn = pred + (size_t)n * (IMG_H * IMG_W) + c;
    const float* tn = targ + (size_t)n * (IMG_H * IMG_W) + c;

    const int a_up = ((lane - 1) & 63) << 2;
    const int a_dn = ((lane + 1) & 63) << 2;
    const bool l0  = (lane == 0);
    const bool l63 = (lane == 63);

    float4 WP[8], WT[8];        // slot = (j - (r0-3)) & 7
    float acc = 0.f;

#define LOADROW(SLOT, J) { \
    const int j_ = (J); \
    if ((unsigned)j_ < (unsigned)IMG_H) { \
        WP[SLOT] = *(const float4*)(pn + j_ * IMG_W); \
        WT[SLOT] = *(const float4*)(tn + j_ * IMG_W); \
    } else { \
        WP[SLOT] = make_float4(0.f, 0.f, 0.f, 0.f); \
        WT[SLOT] = make_float4(0.f, 0.f, 0.f, 0.f); \
    } }

#define VPASS1(D, OUTV, ARR) { \
    OUTV = f4scale(g[0], ARR[(D) & 7]); \
    OUTV = f4fma(g[1], ARR[((D) + 1) & 7], OUTV); \
    OUTV = f4fma(g[2], ARR[((D) + 2) & 7], OUTV); \
    OUTV = f4fma(g[3], ARR[((D) + 3) & 7], OUTV); \
    OUTV = f4fma(g[4], ARR[((D) + 4) & 7], OUTV); \
    OUTV = f4fma(g[5], ARR[((D) + 5) & 7], OUTV); \
    OUTV = f4fma(g[6], ARR[((D) + 6) & 7], OUTV); }

#define VPASS2(D, OUTV, A, B) { \
    OUTV = f4scale(g[0], f4mul(A[(D) & 7], B[(D) & 7])); \
    OUTV = f4fma(g[1], f4mul(A[((D) + 1) & 7], B[((D) + 1) & 7]), OUTV); \
    OUTV = f4fma(g[2], f4mul(A[((D) + 2) & 7], B[((D) + 2) & 7]), OUTV); \
    OUTV = f4fma(g[3], f4mul(A[((D) + 3) & 7], B[((D) + 3) & 7]), OUTV); \
    OUTV = f4fma(g[4], f4mul(A[((D) + 4) & 7], B[((D) + 4) & 7]), OUTV); \
    OUTV = f4fma(g[5], f4mul(A[((D) + 5) & 7], B[((D) + 5) & 7]), OUTV); \
    OUTV = f4fma(g[6], f4mul(A[((D) + 6) & 7], B[((D) + 6) & 7]), OUTV); }

// horizontal 7-tap of V (float4): 6 bpermute halo cols + 4 fma chains
#define HCONV(V, OUT) { \
    float m3 = l0  ? 0.f : pullf(a_up, (V).y); \
    float m2 = l0  ? 0.f : pullf(a_up, (V).z); \
    float m1 = l0  ? 0.f : pullf(a_up, (V).w); \
    float q4 = l63 ? 0.f : pullf(a_dn, (V).x); \
    float q5 = l63 ? 0.f : pullf(a_dn, (V).y); \
    float q6 = l63 ? 0.f : pullf(a_dn, (V).z); \
    (OUT).x = fmaf(g[0], m3, fmaf(g[1], m2, fmaf(g[2], m1, fmaf(g[3], (V).x, \
              fmaf(g[4], (V).y, fmaf(g[5], (V).z, g[6] * (V).w)))))); \
    (OUT).y = fmaf(g[0], m2, fmaf(g[1], m1, fmaf(g[2], (V).x, fmaf(g[3], (V).y, \
              fmaf(g[4], (V).z, fmaf(g[5], (V).w, g[6] * q4)))))); \
    (OUT).z = fmaf(g[0], m1, fmaf(g[1], (V).x, fmaf(g[2], (V).y, fmaf(g[3], (V).z, \
              fmaf(g[4], (V).w, fmaf(g[5], q4, g[6] * q5)))))); \
    (OUT).w = fmaf(g[0], (V).x, fmaf(g[1], (V).y, fmaf(g[2], (V).z, fmaf(g[3], (V).w, \
              fmaf(g[4], q4, fmaf(g[5], q5, g[6] * q6)))))); }

// one output row r0+D. Quantities sequential; SB() after each pair pins the
// live-set (v + current h only). Loads issue at step start (fence below
// keeps them from sinking), giving a full step of prefetch distance.
#define STEP(D, DOLOAD) { \
    if (DOLOAD) { LOADROW(((D) + 7) & 7, r0 + (D) + 4); } \
    float4 v, h0, h1, h2, h3, h4; \
    VPASS1(D, v, WP);     HCONV(v, h0); SB(); \
    VPASS1(D, v, WT);     HCONV(v, h1); SB(); \
    VPASS2(D, v, WP, WP); HCONV(v, h2); SB(); \
    VPASS2(D, v, WT, WT); HCONV(v, h3); SB(); \
    VPASS2(D, v, WP, WT); HCONV(v, h4); SB(); \
    float s0_ = ssim1(h0.x, h1.x, h2.x, h3.x, h4.x); \
    float s1_ = ssim1(h0.y, h1.y, h2.y, h3.y, h4.y); \
    float s2_ = ssim1(h0.z, h1.z, h2.z, h3.z, h4.z); \
    float s3_ = ssim1(h0.w, h1.w, h2.w, h3.w, h4.w); \
    acc += (s0_ + s1_) + (s2_ + s3_); \
    SB(); }

    // prologue: pure loads, rows r0-3 .. r0+3 -> slots 0..6
    LOADROW(0, r0 - 3) LOADROW(1, r0 - 2) LOADROW(2, r0 - 1)
    LOADROW(3, r0)     LOADROW(4, r0 + 1) LOADROW(5, r0 + 2)
    LOADROW(6, r0 + 3)

    STEP(0, 1) STEP(1, 1) STEP(2, 1) STEP(3, 1)
    STEP(4, 1) STEP(5, 1) STEP(6, 1) STEP(7, 0)

#undef LOADROW
#undef VPASS1
#undef VPASS2
#undef HCONV
#undef STEP

    // wave-local reduce, one write (or atomic) per wave
#pragma unroll
    for (int off = 32; off > 0; off >>= 1)
        acc += __shfl_xor(acc, off, 64);
    if (lane == 0) {
        if (ATOMIC) atomicAdd(&wsum[0], acc);
        else        wsum[gw] = acc;
    }
}

// deterministic f64 tree-reduce of the 4096 per-wave partials
__global__ __launch_bounds__(256) void ssim_final_arr(
    const float* __restrict__ ws, float* __restrict__ out)
{
    __shared__ double sred[4];
    double sm = 0.0;
#pragma unroll
    for (int k = 0; k < NWAVES / 256; ++k)
        sm += (double)ws[threadIdx.x + k * 256];
#pragma unroll
    for (int off = 32; off > 0; off >>= 1)
        sm += __shfl_down(sm, off, 64);
    const int lane = threadIdx.x & 63, wid = threadIdx.x >> 6;
    if (lane == 0) sred[wid] = sm;
    __syncthreads();
    if (threadIdx.x == 0) {
        double tot = sred[0] + sred[1] + sred[2] + sred[3];
        out[0] = (float)(1.0 - tot * (1.0 / (128.0 * 256.0 * 256.0)));
    }
}

__global__ void ssim_final_sc(const float* __restrict__ ws, float* __restrict__ out)
{
    out[0] = 1.0f - ws[0] * (1.0f / (128.0f * 256.0f * 256.0f));
}

extern "C" void kernel_launch(void* const* d_in, const int* in_sizes, int n_in,
                              void* d_out, int out_size, void* d_ws, size_t ws_size,
                              hipStream_t stream)
{
    const float* pred   = (const float*)d_in[0];
    const float* targ   = (const float*)d_in[1];
    const float* window = (const float*)d_in[2];
    float* out = (float*)d_out;
    float* ws  = (float*)d_ws;

    if (ws_size >= NWAVES * sizeof(float)) {
        // every ws slot is written by the grid each call: no memset needed
        ssim_main<0><<<NWAVES / 4, 256, 0, stream>>>(pred, targ, window, ws);
        ssim_final_arr<<<1, 256, 0, stream>>>(ws, out);
    } else {
        hipMemsetAsync(ws, 0, sizeof(float), stream);
        ssim_main<1><<<NWAVES / 4, 256, 0, stream>>>(pred, targ, window, ws);
        ssim_final_sc<<<1, 1, 0, stream>>>(ws, out);
    }
    (void)in_sizes; (void)n_in; (void)out_size;
}

// Round 8
// 46.984 us; speedup vs baseline: 1.6294x; 1.6294x over previous
//
#include <hip/hip_runtime.h>

#define IMG_H 256
#define IMG_W 256
#define ROWS 16
#define NIMG 128
#define NWAVES (NIMG * (IMG_H / ROWS) * 2)   // 4096: img x 16 strips x 2 col-halves

__device__ __forceinline__ float ssim1(float mu1, float mu2, float spp, float stt, float spt) {
    const float C1 = 1e-4f, C2 = 9e-4f;
    float mu1s = mu1 * mu1, mu2s = mu2 * mu2, mu12 = mu1 * mu2;
    float s1 = spp - mu1s, s2 = stt - mu2s, s12 = spt - mu12;
    float num = (2.f * mu12 + C1) * (2.f * s12 + C2);
    float den = (mu1s + mu2s + C1) * (s1 + s2 + C2);
    return num * __builtin_amdgcn_rcpf(den);
}

// H-first separable SSIM, LDS-row family (R1 lineage; register-window family
// abandoned after R4-R7: hipcc allocates 248 VGPR for it regardless of
// fences, or spills wholesale under a waves-per-EU min).
//
// One BLOCK = one WAVE (64 threads) = one 16-row x 128-col tile.
// Each thread owns 2 adjacent columns. Per input row:
//   - load own float2 of p and t (+6 halo cols by lanes 0-5)
//   - stage interleaved (p,t) into LDS: one ds_write_b128
//   - read 9-col neighborhood: 4x ds_read_b128 + 1x ds_read_b64 (aligned)
//   - H-conv 5 quantities x 2 cols into mod-7 register window (static idx)
//   - V-conv + SSIM for the completed output row
// Double-buffered LDS row; one __syncthreads (single-wave: cheap fence).
template<int ATOMIC>
__global__ __launch_bounds__(64) void ssim_main(
    const float* __restrict__ pred,
    const float* __restrict__ targ,
    const float* __restrict__ window,
    float* __restrict__ wsum)
{
    __shared__ float2 sbuf[2][136];   // col c at idx c-X0+4; idx0 unused pad

    const int lane = threadIdx.x;     // block == 1 wave
    const int b    = blockIdx.x;
    const int n    = b >> 5;          // image
    const int r    = b & 31;
    const int r0   = (r >> 1) * ROWS; // strip start row
    const int X0   = (r & 1) << 7;    // column half: 0 or 128

    // exact 1D gaussian from w2d row 3: g[j] = w[21+j] / sum
    float g[7];
    {
        float sum = 0.f;
#pragma unroll
        for (int j = 0; j < 7; ++j) { g[j] = window[21 + j]; sum += g[j]; }
        float inv = 1.f / sum;
#pragma unroll
        for (int j = 0; j < 7; ++j) g[j] *= inv;
    }

    const float* pimg = pred + (size_t)n * (IMG_H * IMG_W);
    const float* timg = targ + (size_t)n * (IMG_H * IMG_W);
    const int mo = X0 + 2 * lane;     // own column pair

    // halo duty for lanes 0..5: left cols X0-3..X0-1 (idx 1..3),
    // right cols X0+128..X0+130 (idx 132..134)
    int hidx = 0, hcol = 0;
    if (lane < 3)      { hidx = lane + 1;   hcol = X0 - 3 + lane;   }
    else if (lane < 6) { hidx = lane + 129; hcol = X0 + 125 + lane; }
    const bool hv = (lane < 6) && ((unsigned)hcol < (unsigned)IMG_W);

    // mod-7 register windows: 2 cols x 5 quantities x 7 slots (static idx)
    float Amu[7], Atu[7], App[7], Att[7], Apt[7];
    float Bmu[7], Btu[7], Bpp[7], Btt[7], Bpt[7];
    float acc = 0.f;
    int bufsel = 0;

#define TAP(K, P, T) { \
    float wp = g[K] * (P), wt = g[K] * (T); \
    m_  = fmaf(g[K], (P), m_);  u_  = fmaf(g[K], (T), u_); \
    pp_ = fmaf(wp, (P), pp_);   tt_ = fmaf(wt, (T), tt_); \
    pt_ = fmaf(wp, (T), pt_); }

#define HC(SLOT, MU, TU, PP, TT, PT, p0,p1,p2,p3,p4,p5,p6, t0,t1,t2,t3,t4,t5,t6) { \
    float m_ = 0.f, u_ = 0.f, pp_ = 0.f, tt_ = 0.f, pt_ = 0.f; \
    TAP(0, p0, t0) TAP(1, p1, t1) TAP(2, p2, t2) TAP(3, p3, t3) \
    TAP(4, p4, t4) TAP(5, p5, t5) TAP(6, p6, t6) \
    MU[SLOT] = m_; TU[SLOT] = u_; PP[SLOT] = pp_; TT[SLOT] = tt_; PT[SLOT] = pt_; }

#define VD(A_, U) ( fmaf(g[6], A_[((U)+6)%7], fmaf(g[5], A_[((U)+5)%7], \
    fmaf(g[4], A_[((U)+4)%7], fmaf(g[3], A_[((U)+3)%7], fmaf(g[2], A_[((U)+2)%7], \
    fmaf(g[1], A_[((U)+1)%7], g[0] * A_[(U)%7])))))) )

#define OUTR(U) { \
    { float m1 = VD(Amu,U), m2 = VD(Atu,U), pp = VD(App,U), tt = VD(Att,U), pt = VD(Apt,U); \
      acc += ssim1(m1, m2, pp, tt, pt); } \
    { float m1 = VD(Bmu,U), m2 = VD(Btu,U), pp = VD(Bpp,U), tt = VD(Btt,U), pt = VD(Bpt,U); \
      acc += ssim1(m1, m2, pp, tt, pt); } }

#define STEPX(SLOT, J, HASOUT, U) { \
    const int j_ = (J); \
    const bool inr = ((unsigned)j_ < (unsigned)IMG_H); \
    float2 vp = make_float2(0.f, 0.f), vt = vp, vh = vp; \
    if (inr) { \
        vp = *(const float2*)(pimg + j_ * IMG_W + mo); \
        vt = *(const float2*)(timg + j_ * IMG_W + mo); \
        if (hv) { \
            vh.x = pimg[j_ * IMG_W + hcol]; \
            vh.y = timg[j_ * IMG_W + hcol]; \
        } \
    } \
    { \
        float2* sb = sbuf[bufsel]; \
        *(float4*)(sb + 2 * lane + 4) = make_float4(vp.x, vt.x, vp.y, vt.y); \
        if (lane < 6) sb[hidx] = vh; \
        __syncthreads(); \
        float4 q0 = *(const float4*)(sb + 2 * lane); \
        float4 q1 = *(const float4*)(sb + 2 * lane + 2); \
        float4 q2 = *(const float4*)(sb + 2 * lane + 4); \
        float4 q3 = *(const float4*)(sb + 2 * lane + 6); \
        float2 q4 = sb[2 * lane + 8]; \
        HC(SLOT, Amu, Atu, App, Att, Apt, \
           q0.z, q1.x, q1.z, q2.x, q2.z, q3.x, q3.z, \
           q0.w, q1.y, q1.w, q2.y, q2.w, q3.y, q3.w) \
        HC(SLOT, Bmu, Btu, Bpp, Btt, Bpt, \
           q1.x, q1.z, q2.x, q2.z, q3.x, q3.z, q4.x, \
           q1.y, q1.w, q2.y, q2.w, q3.y, q3.w, q4.y) \
    } \
    bufsel ^= 1; \
    if (HASOUT) { OUTR(U) } }

    // prologue: input rows r0-3 .. r0+2 -> slots 0..5 (no output yet)
    STEPX(0, r0 - 3, 0, 0)
    STEPX(1, r0 - 2, 0, 0)
    STEPX(2, r0 - 1, 0, 0)
    STEPX(3, r0,     0, 0)
    STEPX(4, r0 + 1, 0, 0)
    STEPX(5, r0 + 2, 0, 0)

    // 2 x 7 steady-state steps (slot pattern repeats mod 7)
#pragma unroll 1
    for (int jb = 0; jb < 2; ++jb) {
        const int base = r0 + 3 + jb * 7;
        STEPX(6, base,     1, 0)
        STEPX(0, base + 1, 1, 1)
        STEPX(1, base + 2, 1, 2)
        STEPX(2, base + 3, 1, 3)
        STEPX(3, base + 4, 1, 4)
        STEPX(4, base + 5, 1, 5)
        STEPX(5, base + 6, 1, 6)
    }
    // tail: input rows r0+17, r0+18 -> output rows r0+14, r0+15
    STEPX(6, r0 + 17, 1, 0)
    STEPX(0, r0 + 18, 1, 1)

#undef TAP
#undef HC
#undef VD
#undef OUTR
#undef STEPX

    // wave reduce, one write (or atomic) per wave
#pragma unroll
    for (int off = 32; off > 0; off >>= 1)
        acc += __shfl_xor(acc, off, 64);
    if (lane == 0) {
        if (ATOMIC) atomicAdd(&wsum[0], acc);
        else        wsum[b] = acc;
    }
}

// deterministic f64 tree-reduce of the 4096 per-wave partials
__global__ __launch_bounds__(256) void ssim_final_arr(
    const float* __restrict__ ws, float* __restrict__ out)
{
    __shared__ double sred[4];
    double sm = 0.0;
#pragma unroll
    for (int k = 0; k < NWAVES / 256; ++k)
        sm += (double)ws[threadIdx.x + k * 256];
#pragma unroll
    for (int off = 32; off > 0; off >>= 1)
        sm += __shfl_down(sm, off, 64);
    const int lane = threadIdx.x & 63, wid = threadIdx.x >> 6;
    if (lane == 0) sred[wid] = sm;
    __syncthreads();
    if (threadIdx.x == 0) {
        double tot = sred[0] + sred[1] + sred[2] + sred[3];
        out[0] = (float)(1.0 - tot * (1.0 / (128.0 * 256.0 * 256.0)));
    }
}

__global__ void ssim_final_sc(const float* __restrict__ ws, float* __restrict__ out)
{
    out[0] = 1.0f - ws[0] * (1.0f / (128.0f * 256.0f * 256.0f));
}

extern "C" void kernel_launch(void* const* d_in, const int* in_sizes, int n_in,
                              void* d_out, int out_size, void* d_ws, size_t ws_size,
                              hipStream_t stream)
{
    const float* pred   = (const float*)d_in[0];
    const float* targ   = (const float*)d_in[1];
    const float* window = (const float*)d_in[2];
    float* out = (float*)d_out;
    float* ws  = (float*)d_ws;

    if (ws_size >= NWAVES * sizeof(float)) {
        // every ws slot is written by the grid each call: no memset needed
        ssim_main<0><<<NWAVES, 64, 0, stream>>>(pred, targ, window, ws);
        ssim_final_arr<<<1, 256, 0, stream>>>(ws, out);
    } else {
        hipMemsetAsync(ws, 0, sizeof(float), stream);
        ssim_main<1><<<NWAVES, 64, 0, stream>>>(pred, targ, window, ws);
        ssim_final_sc<<<1, 1, 0, stream>>>(ws, out);
    }
    (void)in_sizes; (void)n_in; (void)out_size;
}

// Round 9
// 46.899 us; speedup vs baseline: 1.6323x; 1.0018x over previous
//
#include <hip/hip_runtime.h>

#define IMG_H 256
#define IMG_W 256
#define ROWS 16
#define NIMG 128
#define NWAVES (NIMG * (IMG_H / ROWS) * 2)   // 4096: img x 16 strips x 2 col-halves

__device__ __forceinline__ float ssim1(float mu1, float mu2, float spp, float stt, float spt) {
    const float C1 = 1e-4f, C2 = 9e-4f;
    float mu1s = mu1 * mu1, mu2s = mu2 * mu2, mu12 = mu1 * mu2;
    float s1 = spp - mu1s, s2 = stt - mu2s, s12 = spt - mu12;
    float num = (2.f * mu12 + C1) * (2.f * s12 + C2);
    float den = (mu1s + mu2s + C1) * (s1 + s2 + C2);
    return num * __builtin_amdgcn_rcpf(den);
}

// H-first separable SSIM, LDS-row family (R8 lineage, occupancy fix).
// 256-thread blocks = 4 independent waves; each wave owns a 16x128 tile and
// a PRIVATE LDS quadrant. NO barriers: DS ops from one wave are processed
// in order by the LDS unit, so same-wave ds_write -> ds_read cross-lane
// handoff needs only the compiler's lgkmcnt wait (R8 used 1-wave blocks +
// __syncthreads: occupancy capped at 18.5%, VALU 40%).
template<int ATOMIC>
__global__ __launch_bounds__(256) void ssim_main(
    const float* __restrict__ pred,
    const float* __restrict__ targ,
    const float* __restrict__ window,
    float* __restrict__ wsum)
{
    __shared__ float2 sbuf[4][2][136];   // [wave][dbuf][col c at idx c-X0+4]

    const int lane = threadIdx.x & 63;
    const int wid  = threadIdx.x >> 6;
    const int gw   = blockIdx.x * 4 + wid;   // 0..4095
    const int n    = gw >> 5;                // image
    const int r    = gw & 31;
    const int r0   = (r >> 1) * ROWS;        // strip start row
    const int X0   = (r & 1) << 7;           // column half: 0 or 128

    // exact 1D gaussian from w2d row 3: g[j] = w[21+j] / sum
    float g[7];
    {
        float sum = 0.f;
#pragma unroll
        for (int j = 0; j < 7; ++j) { g[j] = window[21 + j]; sum += g[j]; }
        float inv = 1.f / sum;
#pragma unroll
        for (int j = 0; j < 7; ++j) g[j] *= inv;
    }

    const float* pimg = pred + (size_t)n * (IMG_H * IMG_W);
    const float* timg = targ + (size_t)n * (IMG_H * IMG_W);
    const int mo = X0 + 2 * lane;     // own column pair

    // halo duty for lanes 0..5: left cols X0-3..X0-1 (idx 1..3),
    // right cols X0+128..X0+130 (idx 132..134)
    int hidx = 0, hcol = 0;
    if (lane < 3)      { hidx = lane + 1;   hcol = X0 - 3 + lane;   }
    else if (lane < 6) { hidx = lane + 129; hcol = X0 + 125 + lane; }
    const bool hv = (lane < 6) && ((unsigned)hcol < (unsigned)IMG_W);

    // mod-7 register windows: 2 cols x 5 quantities x 7 slots (static idx)
    float Amu[7], Atu[7], App[7], Att[7], Apt[7];
    float Bmu[7], Btu[7], Bpp[7], Btt[7], Bpt[7];
    float acc = 0.f;
    int bufsel = 0;

#define TAP(K, P, T) { \
    float wp = g[K] * (P), wt = g[K] * (T); \
    m_  = fmaf(g[K], (P), m_);  u_  = fmaf(g[K], (T), u_); \
    pp_ = fmaf(wp, (P), pp_);   tt_ = fmaf(wt, (T), tt_); \
    pt_ = fmaf(wp, (T), pt_); }

#define HC(SLOT, MU, TU, PP, TT, PT, p0,p1,p2,p3,p4,p5,p6, t0,t1,t2,t3,t4,t5,t6) { \
    float m_ = 0.f, u_ = 0.f, pp_ = 0.f, tt_ = 0.f, pt_ = 0.f; \
    TAP(0, p0, t0) TAP(1, p1, t1) TAP(2, p2, t2) TAP(3, p3, t3) \
    TAP(4, p4, t4) TAP(5, p5, t5) TAP(6, p6, t6) \
    MU[SLOT] = m_; TU[SLOT] = u_; PP[SLOT] = pp_; TT[SLOT] = tt_; PT[SLOT] = pt_; }

#define VD(A_, U) ( fmaf(g[6], A_[((U)+6)%7], fmaf(g[5], A_[((U)+5)%7], \
    fmaf(g[4], A_[((U)+4)%7], fmaf(g[3], A_[((U)+3)%7], fmaf(g[2], A_[((U)+2)%7], \
    fmaf(g[1], A_[((U)+1)%7], g[0] * A_[(U)%7])))))) )

#define OUTR(U) { \
    { float m1 = VD(Amu,U), m2 = VD(Atu,U), pp = VD(App,U), tt = VD(Att,U), pt = VD(Apt,U); \
      acc += ssim1(m1, m2, pp, tt, pt); } \
    { float m1 = VD(Bmu,U), m2 = VD(Btu,U), pp = VD(Bpp,U), tt = VD(Btt,U), pt = VD(Bpt,U); \
      acc += ssim1(m1, m2, pp, tt, pt); } }

#define STEPX(SLOT, J, HASOUT, U) { \
    const int j_ = (J); \
    const bool inr = ((unsigned)j_ < (unsigned)IMG_H); \
    float2 vp = make_float2(0.f, 0.f), vt = vp, vh = vp; \
    if (inr) { \
        vp = *(const float2*)(pimg + j_ * IMG_W + mo); \
        vt = *(const float2*)(timg + j_ * IMG_W + mo); \
        if (hv) { \
            vh.x = pimg[j_ * IMG_W + hcol]; \
            vh.y = timg[j_ * IMG_W + hcol]; \
        } \
    } \
    { \
        float2* sb = sbuf[wid][bufsel]; \
        *(float4*)(sb + 2 * lane + 4) = make_float4(vp.x, vt.x, vp.y, vt.y); \
        if (lane < 6) sb[hidx] = vh; \
        float4 q0 = *(const float4*)(sb + 2 * lane); \
        float4 q1 = *(const float4*)(sb + 2 * lane + 2); \
        float4 q2 = *(const float4*)(sb + 2 * lane + 4); \
        float4 q3 = *(const float4*)(sb + 2 * lane + 6); \
        float2 q4 = sb[2 * lane + 8]; \
        HC(SLOT, Amu, Atu, App, Att, Apt, \
           q0.z, q1.x, q1.z, q2.x, q2.z, q3.x, q3.z, \
           q0.w, q1.y, q1.w, q2.y, q2.w, q3.y, q3.w) \
        HC(SLOT, Bmu, Btu, Bpp, Btt, Bpt, \
           q1.x, q1.z, q2.x, q2.z, q3.x, q3.z, q4.x, \
           q1.y, q1.w, q2.y, q2.w, q3.y, q3.w, q4.y) \
    } \
    bufsel ^= 1; \
    if (HASOUT) { OUTR(U) } }

    // prologue: input rows r0-3 .. r0+2 -> slots 0..5 (no output yet)
    STEPX(0, r0 - 3, 0, 0)
    STEPX(1, r0 - 2, 0, 0)
    STEPX(2, r0 - 1, 0, 0)
    STEPX(3, r0,     0, 0)
    STEPX(4, r0 + 1, 0, 0)
    STEPX(5, r0 + 2, 0, 0)

    // 2 x 7 steady-state steps (slot pattern repeats mod 7)
#pragma unroll 1
    for (int jb = 0; jb < 2; ++jb) {
        const int base = r0 + 3 + jb * 7;
        STEPX(6, base,     1, 0)
        STEPX(0, base + 1, 1, 1)
        STEPX(1, base + 2, 1, 2)
        STEPX(2, base + 3, 1, 3)
        STEPX(3, base + 4, 1, 4)
        STEPX(4, base + 5, 1, 5)
        STEPX(5, base + 6, 1, 6)
    }
    // tail: input rows r0+17, r0+18 -> output rows r0+14, r0+15
    STEPX(6, r0 + 17, 1, 0)
    STEPX(0, r0 + 18, 1, 1)

#undef TAP
#undef HC
#undef VD
#undef OUTR
#undef STEPX

    // wave reduce, one write (or atomic) per wave
#pragma unroll
    for (int off = 32; off > 0; off >>= 1)
        acc += __shfl_xor(acc, off, 64);
    if (lane == 0) {
        if (ATOMIC) atomicAdd(&wsum[0], acc);
        else        wsum[gw] = acc;
    }
}

// deterministic f64 tree-reduce of the 4096 per-wave partials
__global__ __launch_bounds__(256) void ssim_final_arr(
    const float* __restrict__ ws, float* __restrict__ out)
{
    __shared__ double sred[4];
    double sm = 0.0;
#pragma unroll
    for (int k = 0; k < NWAVES / 256; ++k)
        sm += (double)ws[threadIdx.x + k * 256];
#pragma unroll
    for (int off = 32; off > 0; off >>= 1)
        sm += __shfl_down(sm, off, 64);
    const int lane = threadIdx.x & 63, wid = threadIdx.x >> 6;
    if (lane == 0) sred[wid] = sm;
    __syncthreads();
    if (threadIdx.x == 0) {
        double tot = sred[0] + sred[1] + sred[2] + sred[3];
        out[0] = (float)(1.0 - tot * (1.0 / (128.0 * 256.0 * 256.0)));
    }
}

__global__ void ssim_final_sc(const float* __restrict__ ws, float* __restrict__ out)
{
    out[0] = 1.0f - ws[0] * (1.0f / (128.0f * 256.0f * 256.0f));
}

extern "C" void kernel_launch(void* const* d_in, const int* in_sizes, int n_in,
                              void* d_out, int out_size, void* d_ws, size_t ws_size,
                              hipStream_t stream)
{
    const float* pred   = (const float*)d_in[0];
    const float* targ   = (const float*)d_in[1];
    const float* window = (const float*)d_in[2];
    float* out = (float*)d_out;
    float* ws  = (float*)d_ws;

    if (ws_size >= NWAVES * sizeof(float)) {
        // every ws slot is written by the grid each call: no memset needed
        ssim_main<0><<<NWAVES / 4, 256, 0, stream>>>(pred, targ, window, ws);
        ssim_final_arr<<<1, 256, 0, stream>>>(ws, out);
    } else {
        hipMemsetAsync(ws, 0, sizeof(float), stream);
        ssim_main<1><<<NWAVES / 4, 256, 0, stream>>>(pred, targ, window, ws);
        ssim_final_sc<<<1, 1, 0, stream>>>(ws, out);
    }
    (void)in_sizes; (void)n_in; (void)out_size;
}